// Round 1
// baseline (692.524 us; speedup 1.0000x reference)
//
#include <hip/hip_runtime.h>
#include <math.h>

// Problem constants (from reference)
#define Bc 4
#define Nc 512
#define Pc 1024
#define Kc 20
#define SH_DIM 9
#define MUL 64
#define NBc 20
#define HID 100
#define Tc 3
#define CUTc 4.0f
#define Ec (Nc * Kc)       /* 10240 */
#define PEc (Pc * Kc)      /* 20480 */
#define NA (Bc * Nc)       /* 2048 */
#define NP (Bc * Pc)       /* 4096 */
#define ET (Bc * Ec)       /* 40960 */
#define PET (Bc * PEc)     /* 81920 */
#define FEAT (SH_DIM * MUL) /* 576 */

__device__ __forceinline__ float silu_f(float x) { return x / (1.0f + expf(-x)); }
__device__ __forceinline__ float sigmoid_f(float x) { return 1.0f / (1.0f + expf(-x)); }

// ---------------------------------------------------------------------------
// Edge geometry: displacement, edge vector, spherical harmonics, RBF, counts
// ---------------------------------------------------------------------------
__global__ void geom_kernel(const float* __restrict__ pos_src,   // (n_src_tot,3)
                            const float* __restrict__ pos_dst,   // (n_dst_tot,3)
                            const int*   __restrict__ edges,     // (Etot,2) local idx
                            const float* __restrict__ displ,     // (Etot,3)
                            const float* __restrict__ cell,      // (B,3,3)
                            float* __restrict__ sh_out,          // (Etot,9)
                            float* __restrict__ rbf_out,         // (Etot,20)
                            int*   __restrict__ src_out,         // (Etot)
                            int*   __restrict__ cnt,             // (n_dst_tot)
                            int Eper, int Etot, int src_stride, int dst_stride)
{
    int e = blockIdx.x * blockDim.x + threadIdx.x;
    if (e >= Etot) return;
    int b = e / Eper;
    int sl = edges[e * 2 + 0];
    int dl = edges[e * 2 + 1];
    int sg = sl + b * src_stride;
    int dg = dl + b * dst_stride;
    const float* C = cell + b * 9;
    float d0 = displ[e * 3 + 0], d1 = displ[e * 3 + 1], d2 = displ[e * 3 + 2];
    float dx = d0 * C[0] + d1 * C[3] + d2 * C[6];
    float dy = d0 * C[1] + d1 * C[4] + d2 * C[7];
    float dz = d0 * C[2] + d1 * C[5] + d2 * C[8];
    float vx = pos_dst[dg * 3 + 0] - (pos_src[sg * 3 + 0] + dx);
    float vy = pos_dst[dg * 3 + 1] - (pos_src[sg * 3 + 1] + dy);
    float vz = pos_dst[dg * 3 + 2] - (pos_src[sg * 3 + 2] + dz);
    float r = sqrtf(vx * vx + vy * vy + vz * vz);
    float inv = 1.0f / fmaxf(r, 1e-9f);
    float x = vx * inv, y = vy * inv, z = vz * inv;
    const float s3 = 1.7320508075688772f;
    const float s5 = 2.23606797749979f;
    const float s15 = 3.872983346207417f;
    float* sh = sh_out + e * 9;
    sh[0] = 1.0f;
    sh[1] = s3 * x;
    sh[2] = s3 * y;
    sh[3] = s3 * z;
    sh[4] = s15 * x * y;
    sh[5] = s15 * y * z;
    sh[6] = 0.5f * s5 * (3.0f * z * z - 1.0f);
    sh[7] = s15 * x * z;
    sh[8] = 0.5f * s15 * (x * x - y * y);
    const float step = CUTc / (NBc - 1);     // linspace(0,CUT,NB)
    const float inv_sigma = (float)NBc / CUTc; // 1/sigma, sigma=CUT/NB
    float* rb = rbf_out + e * 20;
#pragma unroll
    for (int k = 0; k < NBc; ++k) {
        float t = (r - k * step) * inv_sigma;
        rb[k] = expf(-t * t);
    }
    src_out[e] = sg;
    atomicAdd(&cnt[dg], 1);
}

// ---------------------------------------------------------------------------
// Single-block exclusive scan over counts -> offsets (+cursor copy)
// ---------------------------------------------------------------------------
__global__ void scan_kernel(const int* __restrict__ cnt, int* __restrict__ off,
                            int* __restrict__ cur, int n)
{
    __shared__ int part[256];
    int t = threadIdx.x;
    int per = (n + 255) / 256;
    int lo = t * per, hi = min(lo + per, n);
    int s = 0;
    for (int i = lo; i < hi; ++i) s += cnt[i];
    part[t] = s;
    __syncthreads();
    if (t == 0) {
        int run = 0;
        for (int i = 0; i < 256; ++i) { int v = part[i]; part[i] = run; run += v; }
        off[n] = run;
    }
    __syncthreads();
    int run = part[t];
    for (int i = lo; i < hi; ++i) { off[i] = run; cur[i] = run; run += cnt[i]; }
}

__global__ void fill_kernel(const int* __restrict__ edges, int* __restrict__ cur,
                            int* __restrict__ elist, int Eper, int Etot, int dst_stride)
{
    int e = blockIdx.x * blockDim.x + threadIdx.x;
    if (e >= Etot) return;
    int b = e / Eper;
    int dg = edges[e * 2 + 1] + b * dst_stride;
    int pos = atomicAdd(&cur[dg], 1);
    elist[pos] = e;
}

// ---------------------------------------------------------------------------
// Embedding: h0[a,0,:] = W_embed[nodes[a]], rest zero
// ---------------------------------------------------------------------------
__global__ void embed_kernel(const int* __restrict__ nodes, const float* __restrict__ Wemb,
                             float* __restrict__ h0)
{
    int idx = blockIdx.x * blockDim.x + threadIdx.x;
    if (idx >= NA * FEAT) return;
    int a = idx / FEAT;
    int r = idx % FEAT;
    int i = r / MUL;
    int c = r % MUL;
    h0[idx] = (i == 0) ? Wemb[nodes[a] * MUL + c] : 0.0f;
}

// ---------------------------------------------------------------------------
// Fused conv layer: one wave per destination node, lane = channel.
//   edge MLP (rbf->100 silu ->64) + message + segment sum (gather over CSR)
//   + per-l linear + gate + activation + residual/accumulate.
// outb[n] = base[n] + conv_out[n]   (base may alias outb)
// ---------------------------------------------------------------------------
__global__ __launch_bounds__(64) void conv_kernel(
    const float* __restrict__ h_src,   // (n_src,9,64)
    const float* __restrict__ base,    // (n_out,9,64)
    float* __restrict__ outb,          // (n_out,9,64)
    const int* __restrict__ off, const int* __restrict__ elist,
    const int* __restrict__ srcg,
    const float* __restrict__ sh, const float* __restrict__ rbf,
    const float* __restrict__ Wr1, const float* __restrict__ br1,
    const float* __restrict__ Wr2, const float* __restrict__ br2,
    const float* __restrict__ Wl, const float* __restrict__ Wg)
{
    int n = blockIdx.x;
    int c = threadIdx.x;
    __shared__ float s_rbf[NBc];
    __shared__ float s_sh[SH_DIM];
    __shared__ float s_hid[HID];
    __shared__ float s_a[FEAT];

    float acc[SH_DIM];
#pragma unroll
    for (int i = 0; i < SH_DIM; ++i) acc[i] = 0.0f;

    int e0 = off[n], e1 = off[n + 1];
    float br2c = br2[c];
    float br1c = br1[c];
    float br1c2 = (c < HID - MUL) ? br1[c + MUL] : 0.0f;

    for (int p = e0; p < e1; ++p) {
        int e = elist[p];
        if (c < NBc) s_rbf[c] = rbf[e * NBc + c];
        else if (c < NBc + SH_DIM) s_sh[c - NBc] = sh[e * SH_DIM + (c - NBc)];
        __syncthreads();
        // hidden layer: neuron c and neuron c+64 (lanes 0..35)
        float h1 = br1c;
#pragma unroll
        for (int k = 0; k < NBc; ++k) h1 += s_rbf[k] * Wr1[k * HID + c];
        s_hid[c] = silu_f(h1);
        if (c < HID - MUL) {
            int j = c + MUL;
            float h2 = br1c2;
#pragma unroll
            for (int k = 0; k < NBc; ++k) h2 += s_rbf[k] * Wr1[k * HID + j];
            s_hid[j] = silu_f(h2);
        }
        __syncthreads();
        float wv = br2c;
#pragma unroll
        for (int j = 0; j < HID; ++j) wv += s_hid[j] * Wr2[j * MUL + c];
        float sval = h_src[srcg[e] * FEAT + c];
        float sw = sval * wv;
#pragma unroll
        for (int i = 0; i < SH_DIM; ++i) acc[i] += s_sh[i] * sw;
        __syncthreads();  // protect LDS for next edge
    }

    const float inv_sqrt_k = 0.22360679774997896f;  // 1/sqrt(20)
#pragma unroll
    for (int i = 0; i < SH_DIM; ++i) s_a[i * MUL + c] = acc[i] * inv_sqrt_k;
    __syncthreads();

    // gate = sigmoid(a[0,:] @ Wg)
    float g = 0.0f;
#pragma unroll 8
    for (int cp = 0; cp < MUL; ++cp) g += s_a[cp] * Wg[cp * MUL + c];
    g = sigmoid_f(g);

    // per-l linear + activation + residual
#pragma unroll
    for (int i = 0; i < SH_DIM; ++i) {
        int l = (i == 0) ? 0 : ((i < 4) ? 1 : 2);
        const float* W = Wl + l * MUL * MUL;
        float u = 0.0f;
#pragma unroll 8
        for (int cp = 0; cp < MUL; ++cp) u += s_a[i * MUL + cp] * W[cp * MUL + c];
        float o = (i == 0) ? silu_f(u) : u * g;
        int idx = n * FEAT + i * MUL + c;
        outb[idx] = base[idx] + o;
    }
}

// ---------------------------------------------------------------------------
// out[n] = dot(p[n,0,:], W_out[:,0])
// ---------------------------------------------------------------------------
__global__ __launch_bounds__(64) void out_kernel(const float* __restrict__ p,
                                                 const float* __restrict__ Wout,
                                                 float* __restrict__ out)
{
    int n = blockIdx.x;
    int c = threadIdx.x;
    float v = p[n * FEAT + c] * Wout[c];
#pragma unroll
    for (int o = 32; o > 0; o >>= 1) v += __shfl_down(v, o, 64);
    if (c == 0) out[n] = v;
}

// ---------------------------------------------------------------------------
extern "C" void kernel_launch(void* const* d_in, const int* in_sizes, int n_in,
                              void* d_out, int out_size, void* d_ws, size_t ws_size,
                              hipStream_t stream)
{
    const float* atom_xyz  = (const float*)d_in[0];
    const float* a_disp    = (const float*)d_in[1];
    const float* cell      = (const float*)d_in[2];
    const float* probe_xyz = (const float*)d_in[3];
    const float* p_disp    = (const float*)d_in[4];
    const float* W_embed   = (const float*)d_in[5];
    const float* Wr1       = (const float*)d_in[6];
    const float* br1       = (const float*)d_in[7];
    const float* Wr2       = (const float*)d_in[8];
    const float* br2       = (const float*)d_in[9];
    const float* Wl        = (const float*)d_in[10];
    const float* Wg        = (const float*)d_in[11];
    const float* pWr1      = (const float*)d_in[12];
    const float* pbr1      = (const float*)d_in[13];
    const float* pWr2      = (const float*)d_in[14];
    const float* pbr2      = (const float*)d_in[15];
    const float* pWl       = (const float*)d_in[16];
    const float* pWg       = (const float*)d_in[17];
    const float* W_out     = (const float*)d_in[18];
    const int*   atom_edges  = (const int*)d_in[19];
    const int*   probe_edges = (const int*)d_in[20];
    const int*   nodes       = (const int*)d_in[21];
    float* out = (float*)d_out;

    // workspace layout
    char* w = (char*)d_ws;
    auto alloc = [&](size_t bytes) -> void* {
        void* r = (void*)w;
        w += (bytes + 255) & ~(size_t)255;
        return r;
    };
    float* sh_a   = (float*)alloc((size_t)ET * 9 * 4);
    float* rbf_a  = (float*)alloc((size_t)ET * 20 * 4);
    int*   src_a  = (int*)alloc((size_t)ET * 4);
    int*   cnt_a  = (int*)alloc((size_t)NA * 4);
    int*   off_a  = (int*)alloc((size_t)(NA + 1) * 4);
    int*   cur_a  = (int*)alloc((size_t)NA * 4);
    int*   elist_a= (int*)alloc((size_t)ET * 4);
    float* sh_p   = (float*)alloc((size_t)PET * 9 * 4);
    float* rbf_p  = (float*)alloc((size_t)PET * 20 * 4);
    int*   src_p  = (int*)alloc((size_t)PET * 4);
    int*   cnt_p  = (int*)alloc((size_t)NP * 4);
    int*   off_p  = (int*)alloc((size_t)(NP + 1) * 4);
    int*   cur_p  = (int*)alloc((size_t)NP * 4);
    int*   elist_p= (int*)alloc((size_t)PET * 4);
    float* h0     = (float*)alloc((size_t)NA * FEAT * 4);
    float* rep0   = (float*)alloc((size_t)NA * FEAT * 4);
    float* rep1   = (float*)alloc((size_t)NA * FEAT * 4);
    float* rep2   = (float*)alloc((size_t)NA * FEAT * 4);
    float* pbuf   = (float*)alloc((size_t)NP * FEAT * 4);

    hipMemsetAsync(cnt_a, 0, (size_t)NA * 4, stream);
    hipMemsetAsync(cnt_p, 0, (size_t)NP * 4, stream);
    hipMemsetAsync(pbuf, 0, (size_t)NP * FEAT * 4, stream);

    // geometry + counts
    geom_kernel<<<(ET + 255) / 256, 256, 0, stream>>>(
        atom_xyz, atom_xyz, atom_edges, a_disp, cell,
        sh_a, rbf_a, src_a, cnt_a, Ec, ET, Nc, Nc);
    geom_kernel<<<(PET + 255) / 256, 256, 0, stream>>>(
        atom_xyz, probe_xyz, probe_edges, p_disp, cell,
        sh_p, rbf_p, src_p, cnt_p, PEc, PET, Nc, Pc);

    // CSR build
    scan_kernel<<<1, 256, 0, stream>>>(cnt_a, off_a, cur_a, NA);
    scan_kernel<<<1, 256, 0, stream>>>(cnt_p, off_p, cur_p, NP);
    fill_kernel<<<(ET + 255) / 256, 256, 0, stream>>>(atom_edges, cur_a, elist_a, Ec, ET, Nc);
    fill_kernel<<<(PET + 255) / 256, 256, 0, stream>>>(probe_edges, cur_p, elist_p, Pc * Kc, PET, Pc);

    // embedding
    embed_kernel<<<(NA * FEAT + 255) / 256, 256, 0, stream>>>(nodes, W_embed, h0);

    // atom conv layers: reps[t] = h_prev + conv(h_prev)
    const float* hprev = h0;
    float* reps[3] = {rep0, rep1, rep2};
    for (int t = 0; t < Tc; ++t) {
        conv_kernel<<<NA, 64, 0, stream>>>(
            hprev, hprev, reps[t], off_a, elist_a, src_a, sh_a, rbf_a,
            Wr1 + (size_t)t * NBc * HID, br1 + (size_t)t * HID,
            Wr2 + (size_t)t * HID * MUL, br2 + (size_t)t * MUL,
            Wl + (size_t)t * 3 * MUL * MUL, Wg + (size_t)t * MUL * MUL);
        hprev = reps[t];
    }

    // probe conv layers: p += conv(reps[t])
    for (int t = 0; t < Tc; ++t) {
        conv_kernel<<<NP, 64, 0, stream>>>(
            reps[t], pbuf, pbuf, off_p, elist_p, src_p, sh_p, rbf_p,
            pWr1 + (size_t)t * NBc * HID, pbr1 + (size_t)t * HID,
            pWr2 + (size_t)t * HID * MUL, pbr2 + (size_t)t * MUL,
            pWl + (size_t)t * 3 * MUL * MUL, pWg + (size_t)t * MUL * MUL);
    }

    // readout
    out_kernel<<<NP, 64, 0, stream>>>(pbuf, W_out, out);
}